// Round 3
// baseline (671.741 us; speedup 1.0000x reference)
//
#include <hip/hip_runtime.h>
#include <hip/hip_fp16.h>
#include <math.h>

#define NATOMS 25000
#define NPAIRS 400000
#define XSIZE (NATOMS * 32 * 9)   // 7,200,000 floats; radial output follows
#define WPB 16   // waves per block (one block per CU, persistent)

// silu via hw exp2: x / (1 + 2^(-x*log2e))
__device__ __forceinline__ float silu_f(float x) {
    return x / (1.0f + __builtin_amdgcn_exp2f(-1.4426950408889634f * x));
}

// ---------------- K0: fused EW build (25 blocks) + pair counting ----------------
// EW[tab*3200 + z*32 + f]: tab 0 -> w_zij cols 0..31 (atom i), tab 1 -> cols 32..63 (atom j)
__global__ void k_cnt_ew(const int* __restrict__ pidx, int* __restrict__ counts,
                         const float* __restrict__ emb, const float* __restrict__ wz,
                         float* __restrict__ EW) {
    if (blockIdx.x < 25) {
        int t = blockIdx.x * 256 + threadIdx.x;
        if (t >= 2 * 100 * 32) return;
        int tab = t / 3200;
        int rem = t - tab * 3200;
        int z = rem >> 5;
        int f = rem & 31;
        const float* e = emb + z * 32;
        const float* w = wz + f * 64 + tab * 32;
        float acc = 0.f;
#pragma unroll
        for (int k = 0; k < 32; k++) acc += e[k] * w[k];
        EW[t] = acc;
    } else {
        int p = (blockIdx.x - 25) * 256 + threadIdx.x;
        if (p >= NPAIRS) return;
        atomicAdd(&counts[pidx[p]], 1);
    }
}

// ---------------- K1: exclusive scan of counts -> offsets (single block) ----------------
__global__ __launch_bounds__(1024) void k_scan(const int* __restrict__ counts,
                                               int* __restrict__ offsets) {
    __shared__ int part[1024];
    const int t = threadIdx.x;
    const int base = t * 25;  // 1024*25 = 25600 >= NATOMS
    int mysum = 0;
    for (int i = 0; i < 25; i++) {
        int idx = base + i;
        mysum += (idx < NATOMS) ? counts[idx] : 0;
    }
    part[t] = mysum;
    __syncthreads();
    for (int off = 1; off < 1024; off <<= 1) {
        int v = (t >= off) ? part[t - off] : 0;
        __syncthreads();
        part[t] += v;
        __syncthreads();
    }
    int excl = part[t] - mysum;
    for (int i = 0; i < 25; i++) {
        int idx = base + i;
        if (idx < NATOMS) {
            offsets[idx] = excl;
            excl += counts[idx];
        }
    }
    if (t == 1023) offsets[NATOMS] = part[1023];
}

// ---------------- K2: compact, atom-sorted per-slot records ----------------
// qz[slot] = (pair id, packed species); rd4[slot] = (d, rx, ry, rz).
__global__ void k_fill(const int* __restrict__ pidx, const int* __restrict__ anum,
                       const float* __restrict__ r_ij, const float* __restrict__ d_ij,
                       const int* __restrict__ offsets, int* __restrict__ cursor,
                       int2* __restrict__ qz, float4* __restrict__ rd4) {
    int p = blockIdx.x * 256 + threadIdx.x;
    if (p >= NPAIRS) return;
    int a = pidx[p];
    int aj = pidx[NPAIRS + p];
    int j = atomicAdd(&cursor[a], 1);
    int slot = offsets[a] + j;
    qz[slot] = make_int2(p, (anum[a] << 16) | anum[aj]);
    rd4[slot] = make_float4(d_ij[p], r_ij[3 * p], r_ij[3 * p + 1], r_ij[3 * p + 2]);
}

// ---------------- K3: persistent fused pair-coefficient + atom accumulate + epilogue ----
// 256 blocks (1/CU, forced by 108KB LDS), 16 waves each. After one-time weight
// staging + barrier, each wave dynamically grabs atoms from a global counter:
// no static atom<->wave binding, no block-drain tail, no round quantization.
// Per-atom body is unchanged from the verified round-2 kernel (all cross-lane
// ops wave-private; no barriers inside the work loop).
__global__ __launch_bounds__(1024, 4) void k_fused(
    const int2* __restrict__ qz, const float4* __restrict__ rd4,
    const float* __restrict__ EW, const float* __restrict__ b_zij,
    const float* __restrict__ w_I, const float* __restrict__ b_I,
    const float* __restrict__ w_A, const float* __restrict__ b_A,
    const float* __restrict__ w_S, const float* __restrict__ b_S,
    const int* __restrict__ offsets, int* __restrict__ gctr,
    const float* __restrict__ w_t0, const float* __restrict__ w_t1,
    const float* __restrict__ w_t2,
    const float* __restrict__ w_s1, const float* __restrict__ b_s1,
    const float* __restrict__ w_s2, const float* __restrict__ b_s2,
    const float* __restrict__ ln_w, const float* __restrict__ ln_b,
    float* __restrict__ out, float* __restrict__ out_rad) {
    __shared__ float ewl[6400];
    __shared__ float ws1t[32 * 65];
    __shared__ float ws2t[64 * 97];
    __shared__ float wt0t[32 * 33];
    __shared__ float wt1t[32 * 33];
    __shared__ float wt2t[32 * 33];
    __shared__ float h_st[WPB][32];
    __shared__ float h1_st[WPB][64];
    __shared__ float h2_st[WPB][96];
    __shared__ float vals_st[WPB][320];   // 10 comps x 32f; reused as X staging
    __shared__ float rad_st[WPB][64];     // per-wave radial broadcast (transpose point)

    const int tid = threadIdx.x;
    for (int i = tid; i < 6400; i += 1024) ewl[i] = EW[i];
    for (int i = tid; i < 64 * 32; i += 1024) { int o = i >> 5, ff = i & 31; ws1t[ff * 65 + o] = w_s1[i]; }
    for (int i = tid; i < 96 * 64; i += 1024) { int o = i >> 6, k = i & 63; ws2t[k * 97 + o] = w_s2[i]; }
    for (int i = tid; i < 32 * 32; i += 1024) {
        int g = i >> 5, ff = i & 31;
        wt0t[ff * 33 + g] = w_t0[i];
        wt1t[ff * 33 + g] = w_t1[i];
        wt2t[ff * 33 + g] = w_t2[i];
    }

    const int wave = tid >> 6;
    const int lane = tid & 63;
    const int f = lane & 31;
    const int h = lane >> 5;          // k-half / slot parity
    const int sub = h;                // epilogue naming

    // K-split radial matvec weights: 48 VGPRs total
    float wIr[16], wAr[16], wSr[16];
#pragma unroll
    for (int j = 0; j < 16; j++) {
        int k = h * 16 + j;
        wIr[j] = w_I[f * 32 + k];
        wAr[j] = w_A[f * 32 + k];
        wSr[j] = w_S[f * 32 + k];
    }
    const float bIv = b_I[f], bAv = b_A[f], bSv = b_S[f], bzv = b_zij[f];

    const float startc = 0.006737946999085467f;          // exp(-5)
    const float step = (1.0f - startc) * (1.0f / 31.0f);
    const float tmp = 0.0625f * (1.0f - startc);
    const float bconst = 1.0f / (tmp * tmp);
    const float bexp = bconst * 1.4426950408889634f;     // pre-scaled for exp2
    const float center = startc + (float)f * step;

    __syncthreads();
    // ---- no barriers below this line; waves are independent ----

    for (;;) {
        int atom;
        if (lane == 0) atom = atomicAdd(gctr, 1);
        atom = __shfl(atom, 0, 64);
        if (atom >= NATOMS) break;

        float sI = 0.f, vA0 = 0.f, vA1 = 0.f, vA2 = 0.f;
        float Sxx = 0.f, Sxy = 0.f, Sxz = 0.f, Syy = 0.f, Syz = 0.f, Szz = 0.f;

        const int start = offsets[atom];
        const int cnt = offsets[atom + 1] - start;

        if (cnt > 0) {
            const int nit = (cnt + 1) >> 1;
            // one-deep prefetch of the half-wave's own slot record (broadcast lines)
            int t0 = h;
            int s0 = start + (t0 < cnt ? t0 : cnt - 1);
            float4 rv = rd4[s0];
            int2 qv = qz[s0];
            for (int it = 0; it < nit; ++it) {
                const bool valid = (2 * it + h) < cnt;   // only B-half can be invalid
                float4 rvc = rv;
                int2 qvc = qv;
                if (it + 1 < nit) {
                    int tn = 2 * (it + 1) + h;
                    int sn = start + (tn < cnt ? tn : cnt - 1);
                    rv = rd4[sn];
                    qv = qz[sn];
                }

                float d = rvc.x;
                float invd = __builtin_amdgcn_rcpf(d);
                float hx = rvc.y * invd, hy = rvc.z * invd, hz = rvc.w * invd;
                // v_cos_f32 input is in revolutions: cos(2*pi*d) == amdgcn_cosf(d)
                float rcut = (d < 0.5f) ? 0.5f * __builtin_amdgcn_cosf(d) + 0.5f : 0.0f;
                // exp(-10d) = 2^(-10*log2e*d)
                float ee = __builtin_amdgcn_exp2f(-14.426950408889634f * d);
                float diff = ee - center;
                float radf = __builtin_amdgcn_exp2f(-bexp * diff * diff) * rcut;
                if (valid) out_rad[(long)qvc.x * 32 + f] = radf;  // 128B per half-wave

                // transpose via per-wave LDS broadcast: pair A radial at [0..31],
                // pair B at [32..63]; each half reads its K-half (uniform addr ->
                // broadcast, conflict-free)
                rad_st[wave][lane] = radf;
                float pIA = 0.f, pAA = 0.f, pSA = 0.f, pIB = 0.f, pAB = 0.f, pSB = 0.f;
#pragma unroll
                for (int t = 0; t < 4; t++) {
                    float4 ra = *(const float4*)&rad_st[wave][16 * h + 4 * t];
                    float4 rb = *(const float4*)&rad_st[wave][32 + 16 * h + 4 * t];
                    pIA += ra.x * wIr[4*t+0] + ra.y * wIr[4*t+1] + ra.z * wIr[4*t+2] + ra.w * wIr[4*t+3];
                    pAA += ra.x * wAr[4*t+0] + ra.y * wAr[4*t+1] + ra.z * wAr[4*t+2] + ra.w * wAr[4*t+3];
                    pSA += ra.x * wSr[4*t+0] + ra.y * wSr[4*t+1] + ra.z * wSr[4*t+2] + ra.w * wSr[4*t+3];
                    pIB += rb.x * wIr[4*t+0] + rb.y * wIr[4*t+1] + rb.z * wIr[4*t+2] + rb.w * wIr[4*t+3];
                    pAB += rb.x * wAr[4*t+0] + rb.y * wAr[4*t+1] + rb.z * wAr[4*t+2] + rb.w * wAr[4*t+3];
                    pSB += rb.x * wSr[4*t+0] + rb.y * wSr[4*t+1] + rb.z * wSr[4*t+2] + rb.w * wSr[4*t+3];
                }
                float fIA = pIA + __shfl_xor(pIA, 32, 64) + bIv;
                float fAA = pAA + __shfl_xor(pAA, 32, 64) + bAv;
                float fSA = pSA + __shfl_xor(pSA, 32, 64) + bSv;
                float fIB = pIB + __shfl_xor(pIB, 32, 64) + bIv;
                float fAB = pAB + __shfl_xor(pAB, 32, 64) + bAv;
                float fSB = pSB + __shfl_xor(pSB, 32, 64) + bSv;

                float zf = ewl[(qvc.y >> 16) * 32 + f] + ewl[3200 + (qvc.y & 0xffff) * 32 + f] + bzv;
                float C = valid ? (rcut * zf) : 0.0f;    // own pair's rcut; invalid B -> 0
                float aI = (h ? fIB : fIA) * C;
                float aA = (h ? fAB : fAA) * C;
                float aS = (h ? fSB : fSA) * C;

                // immediate in-register accumulation (no fp16 coef round-trip)
                sI += aI;
                vA0 += aA * hx; vA1 += aA * hy; vA2 += aA * hz;
                Sxx += aS * (hx * hx - (1.0f / 3.0f));
                Sxy += aS * (hx * hy);
                Sxz += aS * (hx * hz);
                Syy += aS * (hy * hy - (1.0f / 3.0f));
                Syz += aS * (hy * hz);
                Szz += aS * (hz * hz - (1.0f / 3.0f));
            }
        }

        // combine slot-parity halves
        sI += __shfl_xor(sI, 32, 64);
        vA0 += __shfl_xor(vA0, 32, 64);
        vA1 += __shfl_xor(vA1, 32, 64);
        vA2 += __shfl_xor(vA2, 32, 64);
        Sxx += __shfl_xor(Sxx, 32, 64);
        Sxy += __shfl_xor(Sxy, 32, 64);
        Sxz += __shfl_xor(Sxz, 32, 64);
        Syy += __shfl_xor(Syy, 32, 64);
        Syz += __shfl_xor(Syz, 32, 64);
        Szz += __shfl_xor(Szz, 32, 64);

        // norm2 of I+A+S for feature f
        float M00 = sI + Sxx, M01 = -vA2 + Sxy, M02 = vA1 + Sxz;
        float M10 = vA2 + Sxy, M11 = sI + Syy, M12 = -vA0 + Syz;
        float M20 = -vA1 + Sxz, M21 = vA0 + Syz, M22 = sI + Szz;
        float norm2 = M00 * M00 + M01 * M01 + M02 * M02 + M10 * M10 + M11 * M11 +
                      M12 * M12 + M20 * M20 + M21 * M21 + M22 * M22;

        // LayerNorm over 32 features (each f present in both subs -> /64)
        float mu = norm2;
#pragma unroll
        for (int m = 32; m >= 1; m >>= 1) mu += __shfl_xor(mu, m, 64);
        mu *= (1.0f / 64.0f);
        float dd = norm2 - mu;
        float vv = dd * dd;
#pragma unroll
        for (int m = 32; m >= 1; m >>= 1) vv += __shfl_xor(vv, m, 64);
        vv *= (1.0f / 64.0f);
        float hln = dd * rsqrtf(vv + 1e-5f) * ln_w[f] + ln_b[f];
        if (sub == 0) h_st[wave][f] = hln;

        // MLP1: 64 outputs (same-wave LDS, lockstep-ordered)
        {
            float acc = b_s1[lane];
#pragma unroll
            for (int k = 0; k < 32; k++) acc += h_st[wave][k] * ws1t[k * 65 + lane];
            h1_st[wave][lane] = silu_f(acc);
        }

        // MLP2: 96 outputs
        {
            float acc = b_s2[lane];
            float acc2 = (lane < 32) ? b_s2[64 + lane] : 0.f;
#pragma unroll
            for (int k = 0; k < 64; k++) {
                float hk = h1_st[wave][k];
                acc += hk * ws2t[k * 97 + lane];
                if (lane < 32) acc2 += hk * ws2t[k * 97 + 64 + lane];
            }
            h2_st[wave][lane] = silu_f(acc);
            if (lane < 32) h2_st[wave][64 + lane] = silu_f(acc2);
        }

        // stage per-f tensor components
        if (sub == 0) {
            vals_st[wave][0 * 32 + f] = sI;
            vals_st[wave][1 * 32 + f] = vA0;
            vals_st[wave][2 * 32 + f] = vA1;
            vals_st[wave][3 * 32 + f] = vA2;
            vals_st[wave][4 * 32 + f] = Sxx;
            vals_st[wave][5 * 32 + f] = Sxy;
            vals_st[wave][6 * 32 + f] = Sxz;
            vals_st[wave][7 * 32 + f] = Syy;
            vals_st[wave][8 * 32 + f] = Syz;
            vals_st[wave][9 * 32 + f] = Szz;
        }

        // channel mixing + combine with s3; X staged back into vals_st
        {
            const int g = f;
            float mI = 0.f, mA0 = 0.f, mA1 = 0.f, mA2 = 0.f;
            float mSxx = 0.f, mSxy = 0.f, mSxz = 0.f, mSyy = 0.f, mSyz = 0.f, mSzz = 0.f;
            const float* V = vals_st[wave];
#pragma unroll 8
            for (int ff = 0; ff < 32; ff++) {
                float w0 = wt0t[ff * 33 + g];
                float w1 = wt1t[ff * 33 + g];
                float w2 = wt2t[ff * 33 + g];
                mI += w0 * V[ff];
                mA0 += w1 * V[32 + ff];
                mA1 += w1 * V[64 + ff];
                mA2 += w1 * V[96 + ff];
                mSxx += w2 * V[128 + ff];
                mSxy += w2 * V[160 + ff];
                mSxz += w2 * V[192 + ff];
                mSyy += w2 * V[224 + ff];
                mSyz += w2 * V[256 + ff];
                mSzz += w2 * V[288 + ff];
            }
            float s0 = h2_st[wave][g * 3 + 0];
            float s1 = h2_st[wave][g * 3 + 1];
            float s2 = h2_st[wave][g * 3 + 2];
            float* X = vals_st[wave];
            if (sub == 0) {
                X[g * 9 + 0] = s0 * mI + s2 * mSxx;
                X[g * 9 + 1] = -s1 * mA2 + s2 * mSxy;
                X[g * 9 + 2] = s1 * mA1 + s2 * mSxz;
                X[g * 9 + 3] = s1 * mA2 + s2 * mSxy;
                X[g * 9 + 4] = s0 * mI + s2 * mSyy;
            } else {
                X[g * 9 + 5] = -s1 * mA0 + s2 * mSyz;
                X[g * 9 + 6] = -s1 * mA1 + s2 * mSxz;
                X[g * 9 + 7] = s1 * mA0 + s2 * mSyz;
                X[g * 9 + 8] = s0 * mI + s2 * mSzz;
            }
        }

        // coalesced X write: 288 contiguous floats per atom
        {
            float* dst = out + (long)atom * 288;
            const float* xs = vals_st[wave];
#pragma unroll
            for (int c = 0; c < 5; c++) {
                int i = lane + c * 64;
                if (i < 288) dst[i] = xs[i];
            }
        }
    }
}

extern "C" void kernel_launch(void* const* d_in, const int* in_sizes, int n_in,
                              void* d_out, int out_size, void* d_ws, size_t ws_size,
                              hipStream_t stream) {
    const int* anum = (const int*)d_in[0];
    const int* pidx = (const int*)d_in[1];
    const float* r_ij = (const float*)d_in[2];
    const float* d_ijp = (const float*)d_in[3];
    const float* emb = (const float*)d_in[4];
    const float* w_zij = (const float*)d_in[5];
    const float* b_zij = (const float*)d_in[6];
    const float* w_I = (const float*)d_in[7];
    const float* b_I = (const float*)d_in[8];
    const float* w_A = (const float*)d_in[9];
    const float* b_A = (const float*)d_in[10];
    const float* w_S = (const float*)d_in[11];
    const float* b_S = (const float*)d_in[12];
    const float* w_t0 = (const float*)d_in[13];
    const float* w_t1 = (const float*)d_in[14];
    const float* w_t2 = (const float*)d_in[15];
    const float* w_s1 = (const float*)d_in[16];
    const float* b_s1 = (const float*)d_in[17];
    const float* w_s2 = (const float*)d_in[18];
    const float* b_s2 = (const float*)d_in[19];
    const float* ln_w = (const float*)d_in[20];
    const float* ln_b = (const float*)d_in[21];
    float* out = (float*)d_out;

    // workspace layout, 16B-aligned where vector-loaded
    float* EW = (float*)d_ws;                                   // 6400 f
    int* counts = (int*)(EW + 6400);                            // 25000 i
    int* cursor = counts + NATOMS;                              // 25000 i
    int* gctr = cursor + NATOMS;                                // 1 i (+1 pad)
    int* offsets = gctr + 2;                                    // 25001 i (+1 pad)
    float4* rd4 = (float4*)(offsets + NATOMS + 2);              // 400000 float4 (16B-aligned)
    int2* qz = (int2*)(rd4 + NPAIRS);                           // 400000 int2

    // zero counts + cursor + gctr in one shot (2*NATOMS+2 ints, contiguous)
    hipMemsetAsync(counts, 0, (2 * NATOMS + 2) * sizeof(int), stream);
    k_cnt_ew<<<25 + (NPAIRS + 255) / 256, 256, 0, stream>>>(pidx, counts, emb, w_zij, EW);
    k_scan<<<1, 1024, 0, stream>>>(counts, offsets);
    k_fill<<<(NPAIRS + 255) / 256, 256, 0, stream>>>(pidx, anum, r_ij, d_ijp,
                                                     offsets, cursor, qz, rd4);
    k_fused<<<256, 1024, 0, stream>>>(qz, rd4, EW, b_zij,
                                      w_I, b_I, w_A, b_A, w_S, b_S,
                                      offsets, gctr, w_t0, w_t1, w_t2,
                                      w_s1, b_s1, w_s2, b_s2,
                                      ln_w, ln_b, out, out + XSIZE);
}

// Round 4
// 525.269 us; speedup vs baseline: 1.2789x; 1.2789x over previous
//
#include <hip/hip_runtime.h>
#include <hip/hip_fp16.h>
#include <math.h>

#define NATOMS 25000
#define NPAIRS 400000
#define XSIZE (NATOMS * 32 * 9)   // 7,200,000 floats; radial output follows
#define WPB 16    // waves per block
#define APB 100   // atoms per block (block-local steal pool); 250 blocks total

// silu via hw exp2: x / (1 + 2^(-x*log2e))
__device__ __forceinline__ float silu_f(float x) {
    return x / (1.0f + __builtin_amdgcn_exp2f(-1.4426950408889634f * x));
}

// ---------------- K0: fused EW build (25 blocks) + pair counting ----------------
// EW[tab*3200 + z*32 + f]: tab 0 -> w_zij cols 0..31 (atom i), tab 1 -> cols 32..63 (atom j)
__global__ void k_cnt_ew(const int* __restrict__ pidx, int* __restrict__ counts,
                         const float* __restrict__ emb, const float* __restrict__ wz,
                         float* __restrict__ EW) {
    if (blockIdx.x < 25) {
        int t = blockIdx.x * 256 + threadIdx.x;
        if (t >= 2 * 100 * 32) return;
        int tab = t / 3200;
        int rem = t - tab * 3200;
        int z = rem >> 5;
        int f = rem & 31;
        const float* e = emb + z * 32;
        const float* w = wz + f * 64 + tab * 32;
        float acc = 0.f;
#pragma unroll
        for (int k = 0; k < 32; k++) acc += e[k] * w[k];
        EW[t] = acc;
    } else {
        int p = (blockIdx.x - 25) * 256 + threadIdx.x;
        if (p >= NPAIRS) return;
        atomicAdd(&counts[pidx[p]], 1);
    }
}

// ---------------- K1: exclusive scan of counts -> offsets (single block) ----------------
__global__ __launch_bounds__(1024) void k_scan(const int* __restrict__ counts,
                                               int* __restrict__ offsets) {
    __shared__ int part[1024];
    const int t = threadIdx.x;
    const int base = t * 25;  // 1024*25 = 25600 >= NATOMS
    int mysum = 0;
    for (int i = 0; i < 25; i++) {
        int idx = base + i;
        mysum += (idx < NATOMS) ? counts[idx] : 0;
    }
    part[t] = mysum;
    __syncthreads();
    for (int off = 1; off < 1024; off <<= 1) {
        int v = (t >= off) ? part[t - off] : 0;
        __syncthreads();
        part[t] += v;
        __syncthreads();
    }
    int excl = part[t] - mysum;
    for (int i = 0; i < 25; i++) {
        int idx = base + i;
        if (idx < NATOMS) {
            offsets[idx] = excl;
            excl += counts[idx];
        }
    }
    if (t == 1023) offsets[NATOMS] = part[1023];
}

// ---------------- K2: compact, atom-sorted per-slot records ----------------
// qz[slot] = (pair id, packed species); rd4[slot] = (d, rx, ry, rz).
__global__ void k_fill(const int* __restrict__ pidx, const int* __restrict__ anum,
                       const float* __restrict__ r_ij, const float* __restrict__ d_ij,
                       const int* __restrict__ offsets, int* __restrict__ cursor,
                       int2* __restrict__ qz, float4* __restrict__ rd4) {
    int p = blockIdx.x * 256 + threadIdx.x;
    if (p >= NPAIRS) return;
    int a = pidx[p];
    int aj = pidx[NPAIRS + p];
    int j = atomicAdd(&cursor[a], 1);
    int slot = offsets[a] + j;
    qz[slot] = make_int2(p, (anum[a] << 16) | anum[aj]);
    rd4[slot] = make_float4(d_ij[p], r_ij[3 * p], r_ij[3 * p + 1], r_ij[3 * p + 2]);
}

// ---------------- K3: fused pair-coefficient + atom accumulate + epilogue ----------------
// 250 blocks x 100 consecutive atoms; 16 waves steal atoms from an LDS counter.
// Key fix vs round-3's global-steal regression: the stolen index is hoisted to
// an SGPR via readfirstlane, so offsets[atom]/out+atom*288 stay SCALAR-addressed
// (round 3's VGPR-divergent atom inflated live state -> ~300MB scratch spill
// traffic each way). Block-local pool keeps round-2's slot-segment L2 locality.
// Per-atom body is byte-identical to the verified round-2 kernel.
__global__ __launch_bounds__(1024, 4) void k_fused(
    const int2* __restrict__ qz, const float4* __restrict__ rd4,
    const float* __restrict__ EW, const float* __restrict__ b_zij,
    const float* __restrict__ w_I, const float* __restrict__ b_I,
    const float* __restrict__ w_A, const float* __restrict__ b_A,
    const float* __restrict__ w_S, const float* __restrict__ b_S,
    const int* __restrict__ offsets,
    const float* __restrict__ w_t0, const float* __restrict__ w_t1,
    const float* __restrict__ w_t2,
    const float* __restrict__ w_s1, const float* __restrict__ b_s1,
    const float* __restrict__ w_s2, const float* __restrict__ b_s2,
    const float* __restrict__ ln_w, const float* __restrict__ ln_b,
    float* __restrict__ out, float* __restrict__ out_rad) {
    __shared__ float ewl[6400];
    __shared__ float ws1t[32 * 65];
    __shared__ float ws2t[64 * 97];
    __shared__ float wt0t[32 * 33];
    __shared__ float wt1t[32 * 33];
    __shared__ float wt2t[32 * 33];
    __shared__ float h_st[WPB][32];
    __shared__ float h1_st[WPB][64];
    __shared__ float h2_st[WPB][96];
    __shared__ float vals_st[WPB][320];   // 10 comps x 32f; reused as X staging
    __shared__ float rad_st[WPB][64];     // per-wave radial broadcast (transpose point)
    __shared__ int na_ctr;                // block-local atom steal counter

    const int tid = threadIdx.x;
    if (tid == 0) na_ctr = 0;
    for (int i = tid; i < 6400; i += 1024) ewl[i] = EW[i];
    for (int i = tid; i < 64 * 32; i += 1024) { int o = i >> 5, ff = i & 31; ws1t[ff * 65 + o] = w_s1[i]; }
    for (int i = tid; i < 96 * 64; i += 1024) { int o = i >> 6, k = i & 63; ws2t[k * 97 + o] = w_s2[i]; }
    for (int i = tid; i < 32 * 32; i += 1024) {
        int g = i >> 5, ff = i & 31;
        wt0t[ff * 33 + g] = w_t0[i];
        wt1t[ff * 33 + g] = w_t1[i];
        wt2t[ff * 33 + g] = w_t2[i];
    }

    const int wave = tid >> 6;
    const int lane = tid & 63;
    const int f = lane & 31;
    const int h = lane >> 5;          // k-half / slot parity
    const int sub = h;                // epilogue naming

    // K-split radial matvec weights: 48 VGPRs total
    float wIr[16], wAr[16], wSr[16];
#pragma unroll
    for (int j = 0; j < 16; j++) {
        int k = h * 16 + j;
        wIr[j] = w_I[f * 32 + k];
        wAr[j] = w_A[f * 32 + k];
        wSr[j] = w_S[f * 32 + k];
    }
    const float bIv = b_I[f], bAv = b_A[f], bSv = b_S[f], bzv = b_zij[f];

    const float startc = 0.006737946999085467f;          // exp(-5)
    const float step = (1.0f - startc) * (1.0f / 31.0f);
    const float tmp = 0.0625f * (1.0f - startc);
    const float bconst = 1.0f / (tmp * tmp);
    const float bexp = bconst * 1.4426950408889634f;     // pre-scaled for exp2
    const float center = startc + (float)f * step;

    const int abase = blockIdx.x * APB;

    __syncthreads();
    // ---- no barriers below this line; waves are independent ----

    for (;;) {
        int la = 0;
        if (lane == 0) la = atomicAdd(&na_ctr, 1);     // LDS atomic, one per wave
        la = __builtin_amdgcn_readfirstlane(la);       // -> SGPR: scalar addressing below
        if (la >= APB) break;
        const int atom = abase + la;                   // uniform (SGPR)

        float sI = 0.f, vA0 = 0.f, vA1 = 0.f, vA2 = 0.f;
        float Sxx = 0.f, Sxy = 0.f, Sxz = 0.f, Syy = 0.f, Syz = 0.f, Szz = 0.f;

        const int start = offsets[atom];
        const int cnt = offsets[atom + 1] - start;

        if (cnt > 0) {
            const int nit = (cnt + 1) >> 1;
            // one-deep prefetch of the half-wave's own slot record (broadcast lines)
            int t0 = h;
            int s0 = start + (t0 < cnt ? t0 : cnt - 1);
            float4 rv = rd4[s0];
            int2 qv = qz[s0];
            for (int it = 0; it < nit; ++it) {
                const bool valid = (2 * it + h) < cnt;   // only B-half can be invalid
                float4 rvc = rv;
                int2 qvc = qv;
                if (it + 1 < nit) {
                    int tn = 2 * (it + 1) + h;
                    int sn = start + (tn < cnt ? tn : cnt - 1);
                    rv = rd4[sn];
                    qv = qz[sn];
                }

                float d = rvc.x;
                float invd = __builtin_amdgcn_rcpf(d);
                float hx = rvc.y * invd, hy = rvc.z * invd, hz = rvc.w * invd;
                // v_cos_f32 input is in revolutions: cos(2*pi*d) == amdgcn_cosf(d)
                float rcut = (d < 0.5f) ? 0.5f * __builtin_amdgcn_cosf(d) + 0.5f : 0.0f;
                // exp(-10d) = 2^(-10*log2e*d)
                float ee = __builtin_amdgcn_exp2f(-14.426950408889634f * d);
                float diff = ee - center;
                float radf = __builtin_amdgcn_exp2f(-bexp * diff * diff) * rcut;
                if (valid) out_rad[(long)qvc.x * 32 + f] = radf;  // 128B per half-wave

                // transpose via per-wave LDS broadcast: pair A radial at [0..31],
                // pair B at [32..63]; each half reads its K-half (uniform addr ->
                // broadcast, conflict-free)
                rad_st[wave][lane] = radf;
                float pIA = 0.f, pAA = 0.f, pSA = 0.f, pIB = 0.f, pAB = 0.f, pSB = 0.f;
#pragma unroll
                for (int t = 0; t < 4; t++) {
                    float4 ra = *(const float4*)&rad_st[wave][16 * h + 4 * t];
                    float4 rb = *(const float4*)&rad_st[wave][32 + 16 * h + 4 * t];
                    pIA += ra.x * wIr[4*t+0] + ra.y * wIr[4*t+1] + ra.z * wIr[4*t+2] + ra.w * wIr[4*t+3];
                    pAA += ra.x * wAr[4*t+0] + ra.y * wAr[4*t+1] + ra.z * wAr[4*t+2] + ra.w * wAr[4*t+3];
                    pSA += ra.x * wSr[4*t+0] + ra.y * wSr[4*t+1] + ra.z * wSr[4*t+2] + ra.w * wSr[4*t+3];
                    pIB += rb.x * wIr[4*t+0] + rb.y * wIr[4*t+1] + rb.z * wIr[4*t+2] + rb.w * wIr[4*t+3];
                    pAB += rb.x * wAr[4*t+0] + rb.y * wAr[4*t+1] + rb.z * wAr[4*t+2] + rb.w * wAr[4*t+3];
                    pSB += rb.x * wSr[4*t+0] + rb.y * wSr[4*t+1] + rb.z * wSr[4*t+2] + rb.w * wSr[4*t+3];
                }
                float fIA = pIA + __shfl_xor(pIA, 32, 64) + bIv;
                float fAA = pAA + __shfl_xor(pAA, 32, 64) + bAv;
                float fSA = pSA + __shfl_xor(pSA, 32, 64) + bSv;
                float fIB = pIB + __shfl_xor(pIB, 32, 64) + bIv;
                float fAB = pAB + __shfl_xor(pAB, 32, 64) + bAv;
                float fSB = pSB + __shfl_xor(pSB, 32, 64) + bSv;

                float zf = ewl[(qvc.y >> 16) * 32 + f] + ewl[3200 + (qvc.y & 0xffff) * 32 + f] + bzv;
                float C = valid ? (rcut * zf) : 0.0f;    // own pair's rcut; invalid B -> 0
                float aI = (h ? fIB : fIA) * C;
                float aA = (h ? fAB : fAA) * C;
                float aS = (h ? fSB : fSA) * C;

                // immediate in-register accumulation (no fp16 coef round-trip)
                sI += aI;
                vA0 += aA * hx; vA1 += aA * hy; vA2 += aA * hz;
                Sxx += aS * (hx * hx - (1.0f / 3.0f));
                Sxy += aS * (hx * hy);
                Sxz += aS * (hx * hz);
                Syy += aS * (hy * hy - (1.0f / 3.0f));
                Syz += aS * (hy * hz);
                Szz += aS * (hz * hz - (1.0f / 3.0f));
            }
        }

        // combine slot-parity halves
        sI += __shfl_xor(sI, 32, 64);
        vA0 += __shfl_xor(vA0, 32, 64);
        vA1 += __shfl_xor(vA1, 32, 64);
        vA2 += __shfl_xor(vA2, 32, 64);
        Sxx += __shfl_xor(Sxx, 32, 64);
        Sxy += __shfl_xor(Sxy, 32, 64);
        Sxz += __shfl_xor(Sxz, 32, 64);
        Syy += __shfl_xor(Syy, 32, 64);
        Syz += __shfl_xor(Syz, 32, 64);
        Szz += __shfl_xor(Szz, 32, 64);

        // norm2 of I+A+S for feature f
        float M00 = sI + Sxx, M01 = -vA2 + Sxy, M02 = vA1 + Sxz;
        float M10 = vA2 + Sxy, M11 = sI + Syy, M12 = -vA0 + Syz;
        float M20 = -vA1 + Sxz, M21 = vA0 + Syz, M22 = sI + Szz;
        float norm2 = M00 * M00 + M01 * M01 + M02 * M02 + M10 * M10 + M11 * M11 +
                      M12 * M12 + M20 * M20 + M21 * M21 + M22 * M22;

        // LayerNorm over 32 features (each f present in both subs -> /64)
        float mu = norm2;
#pragma unroll
        for (int m = 32; m >= 1; m >>= 1) mu += __shfl_xor(mu, m, 64);
        mu *= (1.0f / 64.0f);
        float dd = norm2 - mu;
        float vv = dd * dd;
#pragma unroll
        for (int m = 32; m >= 1; m >>= 1) vv += __shfl_xor(vv, m, 64);
        vv *= (1.0f / 64.0f);
        float hln = dd * rsqrtf(vv + 1e-5f) * ln_w[f] + ln_b[f];
        if (sub == 0) h_st[wave][f] = hln;

        // MLP1: 64 outputs (same-wave LDS, lockstep-ordered)
        {
            float acc = b_s1[lane];
#pragma unroll
            for (int k = 0; k < 32; k++) acc += h_st[wave][k] * ws1t[k * 65 + lane];
            h1_st[wave][lane] = silu_f(acc);
        }

        // MLP2: 96 outputs
        {
            float acc = b_s2[lane];
            float acc2 = (lane < 32) ? b_s2[64 + lane] : 0.f;
#pragma unroll
            for (int k = 0; k < 64; k++) {
                float hk = h1_st[wave][k];
                acc += hk * ws2t[k * 97 + lane];
                if (lane < 32) acc2 += hk * ws2t[k * 97 + 64 + lane];
            }
            h2_st[wave][lane] = silu_f(acc);
            if (lane < 32) h2_st[wave][64 + lane] = silu_f(acc2);
        }

        // stage per-f tensor components
        if (sub == 0) {
            vals_st[wave][0 * 32 + f] = sI;
            vals_st[wave][1 * 32 + f] = vA0;
            vals_st[wave][2 * 32 + f] = vA1;
            vals_st[wave][3 * 32 + f] = vA2;
            vals_st[wave][4 * 32 + f] = Sxx;
            vals_st[wave][5 * 32 + f] = Sxy;
            vals_st[wave][6 * 32 + f] = Sxz;
            vals_st[wave][7 * 32 + f] = Syy;
            vals_st[wave][8 * 32 + f] = Syz;
            vals_st[wave][9 * 32 + f] = Szz;
        }

        // channel mixing + combine with s3; X staged back into vals_st
        {
            const int g = f;
            float mI = 0.f, mA0 = 0.f, mA1 = 0.f, mA2 = 0.f;
            float mSxx = 0.f, mSxy = 0.f, mSxz = 0.f, mSyy = 0.f, mSyz = 0.f, mSzz = 0.f;
            const float* V = vals_st[wave];
#pragma unroll 8
            for (int ff = 0; ff < 32; ff++) {
                float w0 = wt0t[ff * 33 + g];
                float w1 = wt1t[ff * 33 + g];
                float w2 = wt2t[ff * 33 + g];
                mI += w0 * V[ff];
                mA0 += w1 * V[32 + ff];
                mA1 += w1 * V[64 + ff];
                mA2 += w1 * V[96 + ff];
                mSxx += w2 * V[128 + ff];
                mSxy += w2 * V[160 + ff];
                mSxz += w2 * V[192 + ff];
                mSyy += w2 * V[224 + ff];
                mSyz += w2 * V[256 + ff];
                mSzz += w2 * V[288 + ff];
            }
            float s0 = h2_st[wave][g * 3 + 0];
            float s1 = h2_st[wave][g * 3 + 1];
            float s2 = h2_st[wave][g * 3 + 2];
            float* X = vals_st[wave];
            if (sub == 0) {
                X[g * 9 + 0] = s0 * mI + s2 * mSxx;
                X[g * 9 + 1] = -s1 * mA2 + s2 * mSxy;
                X[g * 9 + 2] = s1 * mA1 + s2 * mSxz;
                X[g * 9 + 3] = s1 * mA2 + s2 * mSxy;
                X[g * 9 + 4] = s0 * mI + s2 * mSyy;
            } else {
                X[g * 9 + 5] = -s1 * mA0 + s2 * mSyz;
                X[g * 9 + 6] = -s1 * mA1 + s2 * mSxz;
                X[g * 9 + 7] = s1 * mA0 + s2 * mSyz;
                X[g * 9 + 8] = s0 * mI + s2 * mSzz;
            }
        }

        // coalesced X write: 288 contiguous floats per atom (SGPR base: atom uniform)
        {
            float* dst = out + (long)atom * 288;
            const float* xs = vals_st[wave];
#pragma unroll
            for (int c = 0; c < 5; c++) {
                int i = lane + c * 64;
                if (i < 288) dst[i] = xs[i];
            }
        }
    }
}

extern "C" void kernel_launch(void* const* d_in, const int* in_sizes, int n_in,
                              void* d_out, int out_size, void* d_ws, size_t ws_size,
                              hipStream_t stream) {
    const int* anum = (const int*)d_in[0];
    const int* pidx = (const int*)d_in[1];
    const float* r_ij = (const float*)d_in[2];
    const float* d_ijp = (const float*)d_in[3];
    const float* emb = (const float*)d_in[4];
    const float* w_zij = (const float*)d_in[5];
    const float* b_zij = (const float*)d_in[6];
    const float* w_I = (const float*)d_in[7];
    const float* b_I = (const float*)d_in[8];
    const float* w_A = (const float*)d_in[9];
    const float* b_A = (const float*)d_in[10];
    const float* w_S = (const float*)d_in[11];
    const float* b_S = (const float*)d_in[12];
    const float* w_t0 = (const float*)d_in[13];
    const float* w_t1 = (const float*)d_in[14];
    const float* w_t2 = (const float*)d_in[15];
    const float* w_s1 = (const float*)d_in[16];
    const float* b_s1 = (const float*)d_in[17];
    const float* w_s2 = (const float*)d_in[18];
    const float* b_s2 = (const float*)d_in[19];
    const float* ln_w = (const float*)d_in[20];
    const float* ln_b = (const float*)d_in[21];
    float* out = (float*)d_out;

    // workspace layout, 16B-aligned where vector-loaded
    float* EW = (float*)d_ws;                                   // 6400 f
    int* counts = (int*)(EW + 6400);                            // 25000 i
    int* cursor = counts + NATOMS;                              // 25000 i
    int* offsets = cursor + NATOMS;                             // 25002 i (+pad to even)
    float4* rd4 = (float4*)(offsets + NATOMS + 2);              // 400000 float4 (16B-aligned)
    int2* qz = (int2*)(rd4 + NPAIRS);                           // 400000 int2

    hipMemsetAsync(counts, 0, 2 * NATOMS * sizeof(int), stream);  // counts + cursor
    k_cnt_ew<<<25 + (NPAIRS + 255) / 256, 256, 0, stream>>>(pidx, counts, emb, w_zij, EW);
    k_scan<<<1, 1024, 0, stream>>>(counts, offsets);
    k_fill<<<(NPAIRS + 255) / 256, 256, 0, stream>>>(pidx, anum, r_ij, d_ijp,
                                                     offsets, cursor, qz, rd4);
    k_fused<<<(NATOMS + APB - 1) / APB, 1024, 0, stream>>>(qz, rd4, EW, b_zij,
                                                           w_I, b_I, w_A, b_A, w_S, b_S,
                                                           offsets, w_t0, w_t1, w_t2,
                                                           w_s1, b_s1, w_s2, b_s2,
                                                           ln_w, ln_b, out, out + XSIZE);
}

// Round 5
// 388.721 us; speedup vs baseline: 1.7281x; 1.3513x over previous
//
#include <hip/hip_runtime.h>
#include <hip/hip_fp16.h>
#include <math.h>

#define NATOMS 25000
#define NPAIRS 400000
#define XSIZE (NATOMS * 32 * 9)   // 7,200,000 floats; radial output follows
#define WPB 8    // waves per block (512 threads)

// silu via hw exp2: x / (1 + 2^(-x*log2e))
__device__ __forceinline__ float silu_f(float x) {
    return x / (1.0f + __builtin_amdgcn_exp2f(-1.4426950408889634f * x));
}

// ---------------- K0: fused EW build (25 blocks) + pair counting ----------------
// EW[tab*3200 + z*32 + f]: tab 0 -> w_zij cols 0..31 (atom i), tab 1 -> cols 32..63 (atom j)
__global__ void k_cnt_ew(const int* __restrict__ pidx, int* __restrict__ counts,
                         const float* __restrict__ emb, const float* __restrict__ wz,
                         float* __restrict__ EW) {
    if (blockIdx.x < 25) {
        int t = blockIdx.x * 256 + threadIdx.x;
        if (t >= 2 * 100 * 32) return;
        int tab = t / 3200;
        int rem = t - tab * 3200;
        int z = rem >> 5;
        int f = rem & 31;
        const float* e = emb + z * 32;
        const float* w = wz + f * 64 + tab * 32;
        float acc = 0.f;
#pragma unroll
        for (int k = 0; k < 32; k++) acc += e[k] * w[k];
        EW[t] = acc;
    } else {
        int p = (blockIdx.x - 25) * 256 + threadIdx.x;
        if (p >= NPAIRS) return;
        atomicAdd(&counts[pidx[p]], 1);
    }
}

// ---------------- K1: exclusive scan of counts -> offsets (single block) ----------------
__global__ __launch_bounds__(1024) void k_scan(const int* __restrict__ counts,
                                               int* __restrict__ offsets) {
    __shared__ int part[1024];
    const int t = threadIdx.x;
    const int base = t * 25;  // 1024*25 = 25600 >= NATOMS
    int mysum = 0;
    for (int i = 0; i < 25; i++) {
        int idx = base + i;
        mysum += (idx < NATOMS) ? counts[idx] : 0;
    }
    part[t] = mysum;
    __syncthreads();
    for (int off = 1; off < 1024; off <<= 1) {
        int v = (t >= off) ? part[t - off] : 0;
        __syncthreads();
        part[t] += v;
        __syncthreads();
    }
    int excl = part[t] - mysum;
    for (int i = 0; i < 25; i++) {
        int idx = base + i;
        if (idx < NATOMS) {
            offsets[idx] = excl;
            excl += counts[idx];
        }
    }
    if (t == 1023) offsets[NATOMS] = part[1023];
}

// ---------------- K2: compact, atom-sorted per-slot records ----------------
// qz[slot] = (pair id, packed species); rd4[slot] = (d, rx, ry, rz).
__global__ void k_fill(const int* __restrict__ pidx, const int* __restrict__ anum,
                       const float* __restrict__ r_ij, const float* __restrict__ d_ij,
                       const int* __restrict__ offsets, int* __restrict__ cursor,
                       int2* __restrict__ qz, float4* __restrict__ rd4) {
    int p = blockIdx.x * 256 + threadIdx.x;
    if (p >= NPAIRS) return;
    int a = pidx[p];
    int aj = pidx[NPAIRS + p];
    int j = atomicAdd(&cursor[a], 1);
    int slot = offsets[a] + j;
    qz[slot] = make_int2(p, (anum[a] << 16) | anum[aj]);
    rd4[slot] = make_float4(d_ij[p], r_ij[3 * p], r_ij[3 * p + 1], r_ij[3 * p + 2]);
}

// ---------------- K3: fused pair-coefficient + atom accumulate + epilogue ----------------
// Geometry change vs rounds 1-4 (which all allocated 64 VGPRs against ~105 live
// and spilled in the inner pair loop): 512-thread blocks (8 waves), static atom
// per wave, __launch_bounds__(512,4) -> VGPR cap 128. EW is read from global
// (L2-hot 25.6KB, one coalesced line per half-pair) instead of LDS, dropping
// block LDS to ~63KB so 2 blocks/CU keep occupancy at 4 waves/SIMD.
__global__ __launch_bounds__(512, 4) void k_fused(
    const int2* __restrict__ qz, const float4* __restrict__ rd4,
    const float* __restrict__ EW, const float* __restrict__ b_zij,
    const float* __restrict__ w_I, const float* __restrict__ b_I,
    const float* __restrict__ w_A, const float* __restrict__ b_A,
    const float* __restrict__ w_S, const float* __restrict__ b_S,
    const int* __restrict__ offsets,
    const float* __restrict__ w_t0, const float* __restrict__ w_t1,
    const float* __restrict__ w_t2,
    const float* __restrict__ w_s1, const float* __restrict__ b_s1,
    const float* __restrict__ w_s2, const float* __restrict__ b_s2,
    const float* __restrict__ ln_w, const float* __restrict__ ln_b,
    float* __restrict__ out, float* __restrict__ out_rad) {
    __shared__ float ws1t[32 * 65];
    __shared__ float ws2t[64 * 97];
    __shared__ float wt0t[32 * 33];
    __shared__ float wt1t[32 * 33];
    __shared__ float wt2t[32 * 33];
    __shared__ float h_st[WPB][32];
    __shared__ float h1_st[WPB][64];
    __shared__ float h2_st[WPB][96];
    __shared__ float vals_st[WPB][320];   // 10 comps x 32f; reused as X staging
    __shared__ float rad_st[WPB][64];     // per-wave radial broadcast (transpose point)

    const int tid = threadIdx.x;
    for (int i = tid; i < 64 * 32; i += 512) { int o = i >> 5, ff = i & 31; ws1t[ff * 65 + o] = w_s1[i]; }
    for (int i = tid; i < 96 * 64; i += 512) { int o = i >> 6, k = i & 63; ws2t[k * 97 + o] = w_s2[i]; }
    for (int i = tid; i < 32 * 32; i += 512) {
        int g = i >> 5, ff = i & 31;
        wt0t[ff * 33 + g] = w_t0[i];
        wt1t[ff * 33 + g] = w_t1[i];
        wt2t[ff * 33 + g] = w_t2[i];
    }

    const int wave = tid >> 6;
    const int lane = tid & 63;
    const int f = lane & 31;
    const int h = lane >> 5;          // k-half / slot parity
    const int sub = h;                // epilogue naming

    // K-split radial matvec weights: 48 VGPRs total (fits: cap is 128 now)
    float wIr[16], wAr[16], wSr[16];
#pragma unroll
    for (int j = 0; j < 16; j++) {
        int k = h * 16 + j;
        wIr[j] = w_I[f * 32 + k];
        wAr[j] = w_A[f * 32 + k];
        wSr[j] = w_S[f * 32 + k];
    }
    const float bIv = b_I[f], bAv = b_A[f], bSv = b_S[f], bzv = b_zij[f];

    const float startc = 0.006737946999085467f;          // exp(-5)
    const float step = (1.0f - startc) * (1.0f / 31.0f);
    const float tmp = 0.0625f * (1.0f - startc);
    const float bconst = 1.0f / (tmp * tmp);
    const float bexp = bconst * 1.4426950408889634f;     // pre-scaled for exp2
    const float center = startc + (float)f * step;

    __syncthreads();
    // ---- no barriers below this line; waves are independent ----

    const int atom = blockIdx.x * WPB + wave;
    if (atom >= NATOMS) return;

    float sI = 0.f, vA0 = 0.f, vA1 = 0.f, vA2 = 0.f;
    float Sxx = 0.f, Sxy = 0.f, Sxz = 0.f, Syy = 0.f, Syz = 0.f, Szz = 0.f;

    const int start = offsets[atom];
    const int cnt = offsets[atom + 1] - start;

    if (cnt > 0) {
        const int nit = (cnt + 1) >> 1;
        // one-deep prefetch of the half-wave's own slot record (broadcast lines)
        int t0 = h;
        int s0 = start + (t0 < cnt ? t0 : cnt - 1);
        float4 rv = rd4[s0];
        int2 qv = qz[s0];
        for (int it = 0; it < nit; ++it) {
            const bool valid = (2 * it + h) < cnt;   // only B-half can be invalid
            float4 rvc = rv;
            int2 qvc = qv;
            if (it + 1 < nit) {
                int tn = 2 * (it + 1) + h;
                int sn = start + (tn < cnt ? tn : cnt - 1);
                rv = rd4[sn];
                qv = qz[sn];
            }

            float d = rvc.x;
            float invd = __builtin_amdgcn_rcpf(d);
            float hx = rvc.y * invd, hy = rvc.z * invd, hz = rvc.w * invd;
            // v_cos_f32 input is in revolutions: cos(2*pi*d) == amdgcn_cosf(d)
            float rcut = (d < 0.5f) ? 0.5f * __builtin_amdgcn_cosf(d) + 0.5f : 0.0f;
            // exp(-10d) = 2^(-10*log2e*d)
            float ee = __builtin_amdgcn_exp2f(-14.426950408889634f * d);
            float diff = ee - center;
            float radf = __builtin_amdgcn_exp2f(-bexp * diff * diff) * rcut;
            if (valid) out_rad[(long)qvc.x * 32 + f] = radf;  // 128B per half-wave

            // EW lookups from global (L2-hot): issue早 so latency hides under matvec
            float ewa = EW[(qvc.y >> 16) * 32 + f];
            float ewb = EW[3200 + (qvc.y & 0xffff) * 32 + f];

            // transpose via per-wave LDS broadcast: pair A radial at [0..31],
            // pair B at [32..63]; each half reads its K-half (uniform addr ->
            // broadcast, conflict-free)
            rad_st[wave][lane] = radf;
            float pIA = 0.f, pAA = 0.f, pSA = 0.f, pIB = 0.f, pAB = 0.f, pSB = 0.f;
#pragma unroll
            for (int t = 0; t < 4; t++) {
                float4 ra = *(const float4*)&rad_st[wave][16 * h + 4 * t];
                float4 rb = *(const float4*)&rad_st[wave][32 + 16 * h + 4 * t];
                pIA += ra.x * wIr[4*t+0] + ra.y * wIr[4*t+1] + ra.z * wIr[4*t+2] + ra.w * wIr[4*t+3];
                pAA += ra.x * wAr[4*t+0] + ra.y * wAr[4*t+1] + ra.z * wAr[4*t+2] + ra.w * wAr[4*t+3];
                pSA += ra.x * wSr[4*t+0] + ra.y * wSr[4*t+1] + ra.z * wSr[4*t+2] + ra.w * wSr[4*t+3];
                pIB += rb.x * wIr[4*t+0] + rb.y * wIr[4*t+1] + rb.z * wIr[4*t+2] + rb.w * wIr[4*t+3];
                pAB += rb.x * wAr[4*t+0] + rb.y * wAr[4*t+1] + rb.z * wAr[4*t+2] + rb.w * wAr[4*t+3];
                pSB += rb.x * wSr[4*t+0] + rb.y * wSr[4*t+1] + rb.z * wSr[4*t+2] + rb.w * wSr[4*t+3];
            }
            float fIA = pIA + __shfl_xor(pIA, 32, 64) + bIv;
            float fAA = pAA + __shfl_xor(pAA, 32, 64) + bAv;
            float fSA = pSA + __shfl_xor(pSA, 32, 64) + bSv;
            float fIB = pIB + __shfl_xor(pIB, 32, 64) + bIv;
            float fAB = pAB + __shfl_xor(pAB, 32, 64) + bAv;
            float fSB = pSB + __shfl_xor(pSB, 32, 64) + bSv;

            float zf = ewa + ewb + bzv;
            float C = valid ? (rcut * zf) : 0.0f;    // own pair's rcut; invalid B -> 0
            float aI = (h ? fIB : fIA) * C;
            float aA = (h ? fAB : fAA) * C;
            float aS = (h ? fSB : fSA) * C;

            // immediate in-register accumulation (no fp16 coef round-trip)
            sI += aI;
            vA0 += aA * hx; vA1 += aA * hy; vA2 += aA * hz;
            Sxx += aS * (hx * hx - (1.0f / 3.0f));
            Sxy += aS * (hx * hy);
            Sxz += aS * (hx * hz);
            Syy += aS * (hy * hy - (1.0f / 3.0f));
            Syz += aS * (hy * hz);
            Szz += aS * (hz * hz - (1.0f / 3.0f));
        }
    }

    // combine slot-parity halves
    sI += __shfl_xor(sI, 32, 64);
    vA0 += __shfl_xor(vA0, 32, 64);
    vA1 += __shfl_xor(vA1, 32, 64);
    vA2 += __shfl_xor(vA2, 32, 64);
    Sxx += __shfl_xor(Sxx, 32, 64);
    Sxy += __shfl_xor(Sxy, 32, 64);
    Sxz += __shfl_xor(Sxz, 32, 64);
    Syy += __shfl_xor(Syy, 32, 64);
    Syz += __shfl_xor(Syz, 32, 64);
    Szz += __shfl_xor(Szz, 32, 64);

    // norm2 of I+A+S for feature f
    float M00 = sI + Sxx, M01 = -vA2 + Sxy, M02 = vA1 + Sxz;
    float M10 = vA2 + Sxy, M11 = sI + Syy, M12 = -vA0 + Syz;
    float M20 = -vA1 + Sxz, M21 = vA0 + Syz, M22 = sI + Szz;
    float norm2 = M00 * M00 + M01 * M01 + M02 * M02 + M10 * M10 + M11 * M11 +
                  M12 * M12 + M20 * M20 + M21 * M21 + M22 * M22;

    // LayerNorm over 32 features (each f present in both subs -> /64)
    float mu = norm2;
#pragma unroll
    for (int m = 32; m >= 1; m >>= 1) mu += __shfl_xor(mu, m, 64);
    mu *= (1.0f / 64.0f);
    float dd = norm2 - mu;
    float vv = dd * dd;
#pragma unroll
    for (int m = 32; m >= 1; m >>= 1) vv += __shfl_xor(vv, m, 64);
    vv *= (1.0f / 64.0f);
    float hln = dd * rsqrtf(vv + 1e-5f) * ln_w[f] + ln_b[f];
    if (sub == 0) h_st[wave][f] = hln;

    // MLP1: 64 outputs (same-wave LDS, lockstep-ordered)
    {
        float acc = b_s1[lane];
#pragma unroll
        for (int k = 0; k < 32; k++) acc += h_st[wave][k] * ws1t[k * 65 + lane];
        h1_st[wave][lane] = silu_f(acc);
    }

    // MLP2: 96 outputs
    {
        float acc = b_s2[lane];
        float acc2 = (lane < 32) ? b_s2[64 + lane] : 0.f;
#pragma unroll
        for (int k = 0; k < 64; k++) {
            float hk = h1_st[wave][k];
            acc += hk * ws2t[k * 97 + lane];
            if (lane < 32) acc2 += hk * ws2t[k * 97 + 64 + lane];
        }
        h2_st[wave][lane] = silu_f(acc);
        if (lane < 32) h2_st[wave][64 + lane] = silu_f(acc2);
    }

    // stage per-f tensor components
    if (sub == 0) {
        vals_st[wave][0 * 32 + f] = sI;
        vals_st[wave][1 * 32 + f] = vA0;
        vals_st[wave][2 * 32 + f] = vA1;
        vals_st[wave][3 * 32 + f] = vA2;
        vals_st[wave][4 * 32 + f] = Sxx;
        vals_st[wave][5 * 32 + f] = Sxy;
        vals_st[wave][6 * 32 + f] = Sxz;
        vals_st[wave][7 * 32 + f] = Syy;
        vals_st[wave][8 * 32 + f] = Syz;
        vals_st[wave][9 * 32 + f] = Szz;
    }

    // channel mixing + combine with s3; X staged back into vals_st
    {
        const int g = f;
        float mI = 0.f, mA0 = 0.f, mA1 = 0.f, mA2 = 0.f;
        float mSxx = 0.f, mSxy = 0.f, mSxz = 0.f, mSyy = 0.f, mSyz = 0.f, mSzz = 0.f;
        const float* V = vals_st[wave];
#pragma unroll 8
        for (int ff = 0; ff < 32; ff++) {
            float w0 = wt0t[ff * 33 + g];
            float w1 = wt1t[ff * 33 + g];
            float w2 = wt2t[ff * 33 + g];
            mI += w0 * V[ff];
            mA0 += w1 * V[32 + ff];
            mA1 += w1 * V[64 + ff];
            mA2 += w1 * V[96 + ff];
            mSxx += w2 * V[128 + ff];
            mSxy += w2 * V[160 + ff];
            mSxz += w2 * V[192 + ff];
            mSyy += w2 * V[224 + ff];
            mSyz += w2 * V[256 + ff];
            mSzz += w2 * V[288 + ff];
        }
        float s0 = h2_st[wave][g * 3 + 0];
        float s1 = h2_st[wave][g * 3 + 1];
        float s2 = h2_st[wave][g * 3 + 2];
        float* X = vals_st[wave];
        if (sub == 0) {
            X[g * 9 + 0] = s0 * mI + s2 * mSxx;
            X[g * 9 + 1] = -s1 * mA2 + s2 * mSxy;
            X[g * 9 + 2] = s1 * mA1 + s2 * mSxz;
            X[g * 9 + 3] = s1 * mA2 + s2 * mSxy;
            X[g * 9 + 4] = s0 * mI + s2 * mSyy;
        } else {
            X[g * 9 + 5] = -s1 * mA0 + s2 * mSyz;
            X[g * 9 + 6] = -s1 * mA1 + s2 * mSxz;
            X[g * 9 + 7] = s1 * mA0 + s2 * mSyz;
            X[g * 9 + 8] = s0 * mI + s2 * mSzz;
        }
    }

    // coalesced X write: 288 contiguous floats per atom
    {
        float* dst = out + (long)atom * 288;
        const float* xs = vals_st[wave];
#pragma unroll
        for (int c = 0; c < 5; c++) {
            int i = lane + c * 64;
            if (i < 288) dst[i] = xs[i];
        }
    }
}

extern "C" void kernel_launch(void* const* d_in, const int* in_sizes, int n_in,
                              void* d_out, int out_size, void* d_ws, size_t ws_size,
                              hipStream_t stream) {
    const int* anum = (const int*)d_in[0];
    const int* pidx = (const int*)d_in[1];
    const float* r_ij = (const float*)d_in[2];
    const float* d_ijp = (const float*)d_in[3];
    const float* emb = (const float*)d_in[4];
    const float* w_zij = (const float*)d_in[5];
    const float* b_zij = (const float*)d_in[6];
    const float* w_I = (const float*)d_in[7];
    const float* b_I = (const float*)d_in[8];
    const float* w_A = (const float*)d_in[9];
    const float* b_A = (const float*)d_in[10];
    const float* w_S = (const float*)d_in[11];
    const float* b_S = (const float*)d_in[12];
    const float* w_t0 = (const float*)d_in[13];
    const float* w_t1 = (const float*)d_in[14];
    const float* w_t2 = (const float*)d_in[15];
    const float* w_s1 = (const float*)d_in[16];
    const float* b_s1 = (const float*)d_in[17];
    const float* w_s2 = (const float*)d_in[18];
    const float* b_s2 = (const float*)d_in[19];
    const float* ln_w = (const float*)d_in[20];
    const float* ln_b = (const float*)d_in[21];
    float* out = (float*)d_out;

    // workspace layout, 16B-aligned where vector-loaded
    float* EW = (float*)d_ws;                                   // 6400 f
    int* counts = (int*)(EW + 6400);                            // 25000 i
    int* cursor = counts + NATOMS;                              // 25000 i
    int* offsets = cursor + NATOMS;                             // 25002 i (+pad to even)
    float4* rd4 = (float4*)(offsets + NATOMS + 2);              // 400000 float4 (16B-aligned)
    int2* qz = (int2*)(rd4 + NPAIRS);                           // 400000 int2

    hipMemsetAsync(counts, 0, 2 * NATOMS * sizeof(int), stream);  // counts + cursor
    k_cnt_ew<<<25 + (NPAIRS + 255) / 256, 256, 0, stream>>>(pidx, counts, emb, w_zij, EW);
    k_scan<<<1, 1024, 0, stream>>>(counts, offsets);
    k_fill<<<(NPAIRS + 255) / 256, 256, 0, stream>>>(pidx, anum, r_ij, d_ijp,
                                                     offsets, cursor, qz, rd4);
    k_fused<<<(NATOMS + WPB - 1) / WPB, 512, 0, stream>>>(qz, rd4, EW, b_zij,
                                                          w_I, b_I, w_A, b_A, w_S, b_S,
                                                          offsets, w_t0, w_t1, w_t2,
                                                          w_s1, b_s1, w_s2, b_s2,
                                                          ln_w, ln_b, out, out + XSIZE);
}